// Round 5
// baseline (98.613 us; speedup 1.0000x reference)
//
#include <hip/hip_runtime.h>
#include <hip/hip_bf16.h>

// Problem constants (from reference): B=4,S=2048,K=2,C=32,D=128,P=128
#define P_  128
#define C_  32
#define D_  128
#define BS_ 8192          // B*S rows
#define PD_ (P_*D_)       // 16384 floats = 64 KB
#define NB_ 256           // K1 grid (one privatized LDS table per block)

// Kernel 0: zero the global means table (ws is poisoned 0xAA every call).
__global__ __launch_bounds__(256) void zero_means(float* __restrict__ means)
{
    ((float4*)means)[blockIdx.x * 256 + threadIdx.x] = float4{0.f, 0.f, 0.f, 0.f};
}

// Kernel 1: per-block partial means in LDS; epilogue atomically folds the
// LDS table into the single global means table (replaces the old 16MB
// partials round-trip + separate reduce kernel).
// 512 threads = 8 waves; each wave owns rows rbase + 8*j, j=0..3, fully
// prefetched (16 outstanding global loads) so the 4 shuffle->LDS-atomic
// chains overlap instead of serializing.
__global__ __launch_bounds__(512) void scatter_means(
    const int* __restrict__ idx, const float* __restrict__ keys,
    const float* __restrict__ values, float* __restrict__ means)
{
    __shared__ float lmeans[PD_];
    float4* lm4 = (float4*)lmeans;
    const int tid = threadIdx.x;
    for (int i = tid; i < PD_ / 4; i += 512) lm4[i] = float4{0.f, 0.f, 0.f, 0.f};
    __syncthreads();

    const int lane = tid & 63;
    const int wave = tid >> 6;                 // 0..7
    const int rbase = blockIdx.x * 32 + wave;  // rows: rbase + 8*j

    float kv[4], va[4], vb[4];
    int2  ii[4];
    #pragma unroll
    for (int j = 0; j < 4; ++j) {
        const int r = rbase + 8 * j;
        kv[j] = keys[(size_t)r * 64 + lane];          // [K=2,C=32] flat
        ii[j] = ((const int2*)idx)[r];                // both partition ids
        va[j] = values[(size_t)r * D_ + lane];
        vb[j] = values[(size_t)r * D_ + 64 + lane];
    }

    #pragma unroll
    for (int j = 0; j < 4; ++j) {
        float s = kv[j];
        s += __shfl_xor(s, 16);   // reduce within each 32-lane half
        s += __shfl_xor(s, 8);
        s += __shfl_xor(s, 4);
        s += __shfl_xor(s, 2);
        s += __shfl_xor(s, 1);
        const float ks0 = __shfl(s, 0)  * (1.f / 32.f);  // mean_c keys[r,0,:]
        const float ks1 = __shfl(s, 32) * (1.f / 32.f);  // mean_c keys[r,1,:]
        // stride-1 across lanes -> 2 lanes/bank, conflict-free
        atomicAdd(&lmeans[ii[j].x * D_ + lane],      ks0 * va[j]);
        atomicAdd(&lmeans[ii[j].x * D_ + 64 + lane], ks0 * vb[j]);
        atomicAdd(&lmeans[ii[j].y * D_ + lane],      ks1 * va[j]);
        atomicAdd(&lmeans[ii[j].y * D_ + 64 + lane], ks1 * vb[j]);
    }
    __syncthreads();

    // fold LDS table into global means: 32 coalesced atomics per thread
    for (int i = tid; i < PD_; i += 512)
        atomicAdd(&means[i], lmeans[i]);
}

// Kernel 2: thread-per-float4. gid covers BS_*D_/4 = 262144 float4s.
// 32 consecutive lanes share one row -> means gathers are 512B segments.
__global__ __launch_bounds__(256) void emit_out(
    const int* __restrict__ idx, const float* __restrict__ means,
    const float* __restrict__ queries, float* __restrict__ out)
{
    const int gid = blockIdx.x * 256 + threadIdx.x;   // [0, 262144)
    const int row = gid >> 5;                          // 32 float4 per row
    const int d4  = gid & 31;
    const int2 ii = ((const int2*)idx)[row];
    const float4 q = ((const float4*)queries)[gid];
    const float4* m4 = (const float4*)means;
    const float4 a = m4[ii.x * 32 + d4];
    const float4 b = m4[ii.y * 32 + d4];
    float4 o;
    o.x = (a.x + b.x) * q.x;
    o.y = (a.y + b.y) * q.y;
    o.z = (a.z + b.z) * q.z;
    o.w = (a.w + b.w) * q.w;
    ((float4*)out)[gid] = o;
}

extern "C" void kernel_launch(void* const* d_in, const int* in_sizes, int n_in,
                              void* d_out, int out_size, void* d_ws, size_t ws_size,
                              hipStream_t stream) {
    const int*   idx     = (const int*)d_in[0];    // [B,S,K] int32
    const float* keys    = (const float*)d_in[1];  // [B,S,K,C] fp32
    const float* values  = (const float*)d_in[2];  // [B,S,D]  fp32
    const float* queries = (const float*)d_in[3];  // [B,S,D]  fp32
    float* out   = (float*)d_out;
    float* means = (float*)d_ws;                   // 64 KB of ws

    zero_means<<<PD_ / 4 / 256, 256, 0, stream>>>(means);
    scatter_means<<<NB_, 512, 0, stream>>>(idx, keys, values, means);
    emit_out<<<(BS_ * D_ / 4) / 256, 256, 0, stream>>>(idx, means, queries, out);
}

// Round 6
// 96.217 us; speedup vs baseline: 1.0249x; 1.0249x over previous
//
#include <hip/hip_runtime.h>
#include <hip/hip_bf16.h>

// Problem constants (from reference): B=4,S=2048,K=2,C=32,D=128,P=128
#define P_  128
#define C_  32
#define D_  128
#define BS_ 8192          // B*S rows
#define PD_ (P_*D_)       // 16384 floats = 64 KB
#define NB_ 256           // K1 grid (one privatized LDS table per block)
#define NT_ 16            // global partial tables (16 blocks share a table)

// Kernel 0: zero the NT_ global partial tables (ws is poisoned 0xAA).
__global__ __launch_bounds__(256) void zero_tables(float* __restrict__ tables)
{
    ((float4*)tables)[blockIdx.x * 256 + threadIdx.x] = float4{0.f, 0.f, 0.f, 0.f};
}

// Kernel 1: per-block privatized means in LDS; epilogue atomically folds into
// one of NT_ global tables (16-way contention/address instead of R5's 256-way,
// which cost ~16us in same-line serialization across XCDs).
// 512 threads = 8 waves; each wave owns rows rbase + 8*j, j=0..3, fully
// prefetched so the 4 shuffle->LDS-atomic chains overlap.
__global__ __launch_bounds__(512) void scatter_means(
    const int* __restrict__ idx, const float* __restrict__ keys,
    const float* __restrict__ values, float* __restrict__ tables)
{
    __shared__ float lmeans[PD_];
    float4* lm4 = (float4*)lmeans;
    const int tid = threadIdx.x;
    for (int i = tid; i < PD_ / 4; i += 512) lm4[i] = float4{0.f, 0.f, 0.f, 0.f};
    __syncthreads();

    const int lane = tid & 63;
    const int wave = tid >> 6;                 // 0..7
    const int rbase = blockIdx.x * 32 + wave;  // rows: rbase + 8*j

    float kv[4], va[4], vb[4];
    int2  ii[4];
    #pragma unroll
    for (int j = 0; j < 4; ++j) {
        const int r = rbase + 8 * j;
        kv[j] = keys[(size_t)r * 64 + lane];          // [K=2,C=32] flat
        ii[j] = ((const int2*)idx)[r];                // both partition ids
        va[j] = values[(size_t)r * D_ + lane];
        vb[j] = values[(size_t)r * D_ + 64 + lane];
    }

    #pragma unroll
    for (int j = 0; j < 4; ++j) {
        float s = kv[j];
        s += __shfl_xor(s, 16);   // reduce within each 32-lane half
        s += __shfl_xor(s, 8);
        s += __shfl_xor(s, 4);
        s += __shfl_xor(s, 2);
        s += __shfl_xor(s, 1);
        const float ks0 = __shfl(s, 0)  * (1.f / 32.f);  // mean_c keys[r,0,:]
        const float ks1 = __shfl(s, 32) * (1.f / 32.f);  // mean_c keys[r,1,:]
        // stride-1 across lanes -> 2 lanes/bank, conflict-free
        atomicAdd(&lmeans[ii[j].x * D_ + lane],      ks0 * va[j]);
        atomicAdd(&lmeans[ii[j].x * D_ + 64 + lane], ks0 * vb[j]);
        atomicAdd(&lmeans[ii[j].y * D_ + lane],      ks1 * va[j]);
        atomicAdd(&lmeans[ii[j].y * D_ + 64 + lane], ks1 * vb[j]);
    }
    __syncthreads();

    // fold LDS table into this block's shard table: 32 coalesced atomics/thread
    float* tbl = tables + (size_t)(blockIdx.x & (NT_ - 1)) * PD_;
    for (int i = tid; i < PD_; i += 512)
        atomicAdd(&tbl[i], lmeans[i]);
}

// Kernel 2: means[e] = sum over NT_ tables (1 MB, L2-hot). 64 blocks.
__global__ __launch_bounds__(256) void reduce_tables(
    const float* __restrict__ tables, float* __restrict__ means)
{
    const int e = blockIdx.x * 256 + threadIdx.x;   // [0, PD_)
    float s = 0.f;
    #pragma unroll
    for (int t = 0; t < NT_; ++t) s += tables[(size_t)t * PD_ + e];
    means[e] = s;
}

// Kernel 3: thread-per-float4. gid covers BS_*D_/4 = 262144 float4s.
// 32 consecutive lanes share one row -> means gathers are 512B segments.
__global__ __launch_bounds__(256) void emit_out(
    const int* __restrict__ idx, const float* __restrict__ means,
    const float* __restrict__ queries, float* __restrict__ out)
{
    const int gid = blockIdx.x * 256 + threadIdx.x;   // [0, 262144)
    const int row = gid >> 5;                          // 32 float4 per row
    const int d4  = gid & 31;
    const int2 ii = ((const int2*)idx)[row];
    const float4 q = ((const float4*)queries)[gid];
    const float4* m4 = (const float4*)means;
    const float4 a = m4[ii.x * 32 + d4];
    const float4 b = m4[ii.y * 32 + d4];
    float4 o;
    o.x = (a.x + b.x) * q.x;
    o.y = (a.y + b.y) * q.y;
    o.z = (a.z + b.z) * q.z;
    o.w = (a.w + b.w) * q.w;
    ((float4*)out)[gid] = o;
}

extern "C" void kernel_launch(void* const* d_in, const int* in_sizes, int n_in,
                              void* d_out, int out_size, void* d_ws, size_t ws_size,
                              hipStream_t stream) {
    const int*   idx     = (const int*)d_in[0];    // [B,S,K] int32
    const float* keys    = (const float*)d_in[1];  // [B,S,K,C] fp32
    const float* values  = (const float*)d_in[2];  // [B,S,D]  fp32
    const float* queries = (const float*)d_in[3];  // [B,S,D]  fp32
    float* out    = (float*)d_out;
    float* tables = (float*)d_ws;                  // NT_ x 64 KB
    float* means  = tables + (size_t)NT_ * PD_;    // final 64 KB table

    zero_tables<<<(NT_ * PD_ / 4) / 256, 256, 0, stream>>>(tables);
    scatter_means<<<NB_, 512, 0, stream>>>(idx, keys, values, tables);
    reduce_tables<<<PD_ / 256, 256, 0, stream>>>(tables, means);
    emit_out<<<(BS_ * D_ / 4) / 256, 256, 0, stream>>>(idx, means, queries, out);
}